// Round 10
// baseline (176.729 us; speedup 1.0000x reference)
//
#include <hip/hip_runtime.h>

using bf16x8 = __attribute__((ext_vector_type(8))) short;
using f32x4  = __attribute__((ext_vector_type(4))) float;
using i32x4  = __attribute__((ext_vector_type(4))) int;

#define MFMA(a,b,c) __builtin_amdgcn_mfma_f32_16x16x32_bf16((a),(b),(c),0,0,0)

__device__ __forceinline__ short f2bf(float f) {
  unsigned u = __builtin_bit_cast(unsigned, f);
  u += 0x7FFFu + ((u >> 16) & 1u);   // RNE
  return (short)(u >> 16);
}
__device__ __forceinline__ float sigm(float x) { return 1.0f / (1.0f + __expf(-x)); }
__device__ __forceinline__ float tanh_(float x) { return 2.0f * sigm(2.0f * x) - 1.0f; }

__device__ __forceinline__ bf16x8 pack8(float4 a, float4 b) {
  bf16x8 r;
  r[0]=f2bf(a.x); r[1]=f2bf(a.y); r[2]=f2bf(a.z); r[3]=f2bf(a.w);
  r[4]=f2bf(b.x); r[5]=f2bf(b.y); r[6]=f2bf(b.z); r[7]=f2bf(b.w);
  return r;
}

// ---------------- prep: weights -> bf16, MFMA-fragment-tiled layouts ----------------
__global__ void k_prep(const float* __restrict__ w1, const float* __restrict__ w2,
                       const float* __restrict__ w3, const float* __restrict__ wih,
                       const float* __restrict__ whh, const float* __restrict__ aw,
                       const float* __restrict__ lw,
                       short* __restrict__ w1p, short* __restrict__ w2p, short* __restrict__ w3p,
                       short* __restrict__ wihp, short* __restrict__ whhp,
                       short* __restrict__ attnp, short* __restrict__ linp)
{
  int i = blockIdx.x * 256 + threadIdx.x;
  if (i < 8192) {                       // w1p [128][64], k=c*9+dy*3+dx, pad 36..63 = 0
    int o = i >> 6, k = i & 63;
    float v = 0.f;
    if (k < 36) { int c = k / 9, r9 = k % 9; v = w1[((o*4 + c)*3 + r9/3)*3 + (r9%3)]; }
    w1p[i] = f2bf(v); return;
  }
  i -= 8192;
  if (i < 32768) {                      // w2p [64][512], k=(dy*2+dx)*128+c
    int o = i >> 9, k = i & 511;
    int dydx = k >> 7, c = k & 127;
    w2p[i] = f2bf(w2[((o*128 + c)*2 + (dydx>>1))*2 + (dydx&1)]); return;
  }
  i -= 32768;
  if (i < 16384) {                      // w3p [64][256], k=(dy*2+dx)*64+c
    int o = i >> 8, k = i & 255;
    int dydx = k >> 6, c = k & 63;
    w3p[i] = f2bf(w3[((o*64 + c)*2 + (dydx>>1))*2 + (dydx&1)]); return;
  }
  i -= 16384;
  if (i < 24576) {                      // wih2: [rt][kc(0..3)][r16][k8]
    int k8 = i & 7, r16 = (i >> 3) & 15, kc = (i >> 7) & 3, rt = i >> 9;
    wihp[i] = f2bf(wih[(rt*16 + r16) * 32 + kc*8 + k8]); return;
  }
  i -= 24576;
  if (i < 196608) {                     // whh2: [rt(0..47)][kc(0..31)][r16][k8]
    int k8 = i & 7, r16 = (i >> 3) & 15, kc = (i >> 7) & 31, rt = i >> 12;
    whhp[i] = f2bf(whh[(rt*16 + r16) * 256 + kc*8 + k8]); return;
  }
  i -= 196608;
  if (i < 16384) {                      // attn2: [rt(0..3)][kc(0..31)][r16][k8]
    int k8 = i & 7, r16 = (i >> 3) & 15, kc = (i >> 7) & 31, rt = i >> 12;
    attnp[i] = f2bf(aw[(rt*16 + r16) * 256 + kc*8 + k8]); return;
  }
  i -= 16384;
  if (i < 589824) {                     // linp2: [rt(0..15)][kc(0..71)][lane(0..63)][e(0..7)]
    int j = i >> 9;
    int rt = j / 72, kc = j - rt * 72;
    int q = i & 511, lane = q >> 3, e = q & 7;
    int row = rt * 16 + (lane & 15);
    int k = kc * 32 + (lane >> 4) * 8 + e;
    linp[i] = f2bf(lw[row * 2304 + k]); return;
  }
}

// ---------------- GRU: whh pinned (ks0 VGPR, ks1-6 AGPR fed to MFMA directly, ks7 LDS) ----------------
__global__ __launch_bounds__(512, 2) void k_gru(
    const int* __restrict__ inst, const float* __restrict__ emb_w,
    const short* __restrict__ wih2, const short* __restrict__ whh2,
    const float* __restrict__ b_ih, const float* __restrict__ b_hh,
    const short* __restrict__ attn2, const float* __restrict__ attn_b,
    float* __restrict__ attn_out)
{
  __shared__ short hA[16 * 256];       // bf16 h double-buffer, XOR-swizzled (row 512B)
  __shared__ short hB[16 * 256];
  __shared__ short xfL[16 * 64 * 8];   // [t][lane][8]  (16KB)
  __shared__ short wihL[6 * 512 * 8];  // [nt][tid][8]  (48KB)
  __shared__ short wf7L[6 * 512 * 8];  // whh ks=7 fragments (48KB)

  const int tid = threadIdx.x;
  const int w = tid >> 6, l = tid & 63, lr = l & 15, lk = l >> 4;
  const int b0 = blockIdx.x * 16;
  const f32x4 z4 = {0.f, 0.f, 0.f, 0.f};

  int rtile[6], rowW[6];
  #pragma unroll
  for (int nt = 0; nt < 6; ++nt) {
    rtile[nt] = (nt >> 1) * 16 + w * 2 + (nt & 1);
    rowW[nt]  = rtile[nt] * 16 + lr;
  }

  // -------- preload whh: ks0 -> VGPR, ks1..6 -> AGPR (pinned), ks7 -> LDS --------
  bf16x8 wf0[6];
  i32x4 ag[6][6];
  #pragma unroll
  for (int nt = 0; nt < 6; ++nt) {
    wf0[nt] = *(const bf16x8*)(whh2 + ((rtile[nt]*32 + lk)*16 + lr)*8);
    #pragma unroll
    for (int ks = 1; ks < 7; ++ks) {
      bf16x8 t = *(const bf16x8*)(whh2 + ((rtile[nt]*32 + ks*4 + lk)*16 + lr)*8);
      i32x4 u = __builtin_bit_cast(i32x4, t);
      asm("" : "=a"(ag[nt][ks-1]) : "0"(u));   // pin into AGPR tuple
    }
    *(bf16x8*)(wf7L + (nt*512 + tid)*8) =
        *(const bf16x8*)(whh2 + ((rtile[nt]*32 + 28 + lk)*16 + lr)*8);
    *(bf16x8*)(wihL + (nt*512 + tid)*8) =
        *(const bf16x8*)(wih2 + ((rtile[nt]*4 + lk)*16 + lr)*8);
  }

  float biasRZ[4], bihN[2], bhhN[2];
  #pragma unroll
  for (int nt = 0; nt < 4; ++nt) biasRZ[nt] = b_ih[rowW[nt]] + b_hh[rowW[nt]];
  #pragma unroll
  for (int s = 0; s < 2; ++s) { bihN[s] = b_ih[rowW[4+s]]; bhhN[s] = b_hh[rowW[4+s]]; }

  #pragma unroll
  for (int f = tid; f < 1024; f += 512) {
    int t = f >> 6, ll = f & 63, llr = ll & 15, llk = ll >> 4;
    int id = inst[(b0 + llr) * 16 + t];
    const float* ep = emb_w + id * 32 + llk * 8;
    *(bf16x8*)(xfL + f * 8) = pack8(*(const float4*)(ep), *(const float4*)(ep + 4));
  }

  for (int i = tid; i < 4096; i += 512) hA[i] = 0;

  float hOld[2][4];
  #pragma unroll
  for (int s = 0; s < 2; ++s)
    #pragma unroll
    for (int e = 0; e < 4; ++e) hOld[s][e] = 0.f;

  __syncthreads();

  for (int t = 0; t < 16; ++t) {
    const short* hr = (t & 1) ? hB : hA;
    short*       hw = (t & 1) ? hA : hB;

    bf16x8 xf = *(const bf16x8*)(xfL + (t * 64 + l) * 8);
    f32x4 acc[6], gin[2];
    #pragma unroll
    for (int nt = 0; nt < 4; ++nt)
      acc[nt] = MFMA(xf, *(const bf16x8*)(wihL + (nt*512 + tid)*8), z4);
    #pragma unroll
    for (int s = 0; s < 2; ++s)
      gin[s] = MFMA(xf, *(const bf16x8*)(wihL + ((4+s)*512 + tid)*8), z4);
    acc[4] = z4; acc[5] = z4;

    {   // ks = 0 from VGPR
      int byte = (lr * 512 + lk * 16) ^ ((lr & 7) << 4);
      bf16x8 hf = *(const bf16x8*)((const char*)hr + byte);
      #pragma unroll
      for (int nt = 0; nt < 6; ++nt) acc[nt] = MFMA(hf, wf0[nt], acc[nt]);
    }
    #pragma unroll
    for (int ks = 1; ks < 7; ++ks) {    // ks = 1..6: MFMA reads B straight from AGPR
      int byte = (lr * 512 + ks * 64 + lk * 16) ^ ((lr & 7) << 4);
      bf16x8 hf = *(const bf16x8*)((const char*)hr + byte);
      #pragma unroll
      for (int nt = 0; nt < 6; ++nt)
        asm volatile("v_mfma_f32_16x16x32_bf16 %0, %1, %2, %0"
                     : "+v"(acc[nt]) : "v"(hf), "a"(ag[nt][ks-1]));
    }
    {   // ks = 7 from LDS stash
      int byte = (lr * 512 + 7 * 64 + lk * 16) ^ ((lr & 7) << 4);
      bf16x8 hf = *(const bf16x8*)((const char*)hr + byte);
      #pragma unroll
      for (int nt = 0; nt < 6; ++nt) {
        bf16x8 bw = *(const bf16x8*)(wf7L + (nt*512 + tid)*8);
        acc[nt] = MFMA(hf, bw, acc[nt]);
      }
    }

    #pragma unroll
    for (int s = 0; s < 2; ++s)
      #pragma unroll
      for (int e = 0; e < 4; ++e) {
        float r  = sigm(acc[s][e]     + biasRZ[s]);
        float zz = sigm(acc[2 + s][e] + biasRZ[2 + s]);
        float nn = tanh_(gin[s][e] + bihN[s] + r * (acc[4 + s][e] + bhhN[s]));
        float hn = (1.0f - zz) * nn + zz * hOld[s][e];
        hOld[s][e] = hn;
        int row = lk * 4 + e;
        int col = w * 32 + s * 16 + lr;
        int byte = (row * 512 + col * 2) ^ ((row & 7) << 4);
        *(short*)((char*)hw + byte) = f2bf(hn);
      }
    __syncthreads();
  }

  if (w < 4) {
    f32x4 acc = z4;
    #pragma unroll
    for (int ks = 0; ks < 8; ++ks) {
      int byte = (lr * 512 + ks * 64 + lk * 16) ^ ((lr & 7) << 4);
      bf16x8 hf = *(const bf16x8*)((const char*)hA + byte);
      bf16x8 bw = *(const bf16x8*)(attn2 + ((w*32 + ks*4 + lk)*16 + lr)*8);
      acc = MFMA(hf, bw, acc);
    }
    float bb = attn_b[w * 16 + lr];
    #pragma unroll
    for (int e = 0; e < 4; ++e) {
      int row = lk * 4 + e;
      attn_out[(b0 + row) * 64 + w * 16 + lr] = sigm(acc[e] + bb);
    }
  }
}

// ---------------- fused conv1+conv2+conv3 + gating + PE -> flatT ----------------
// 1 sample per block, 256 thr (4 waves). Operand-swapped MFMA (A=weights, B=acts).
// conv2/conv3 weight fragments AGPR-PINNED at kernel entry (96 AGPRs): loads issue
// with full MLP, latency hidden under xb-staging+im2col, allocator cannot remat.
// launch_bounds(256,3): ~170 total regs -> 3 blocks/CU; ILP > TLP for this kernel.
__global__ __launch_bounds__(256, 3) void k_conv(
    const float* __restrict__ x,
    const short* __restrict__ w1p, const float* __restrict__ b1,
    const short* __restrict__ w2p, const float* __restrict__ b2,
    const short* __restrict__ w3p, const float* __restrict__ b3,
    const float* __restrict__ attn, const int* __restrict__ steps,
    short* __restrict__ flatT)
{
  __shared__ short smem[13312];
  short* const A1  = smem;           // [64][72]  im2col [p][k], stride 144B
  short* const a2  = smem;           // [49][72]  [p][oc] (overlays A1)
  short* const xb  = smem + 4608;    // [400] x bf16 (dead after im2col)
  short* const a1  = smem + 4608;    // [64][136] [p][oc], stride 272B (overlays xb)
  short* const fst = smem + 4608;    // [2304]    (overlays a1 after conv2)

  const int tid = threadIdx.x;
  const int w = tid >> 6, l = tid & 63, lc = l & 15, lk = l >> 4;
  const int b = blockIdx.x;
  const f32x4 z4 = {0.f, 0.f, 0.f, 0.f};

  // -------- issue ALL weight loads first; pin conv2/conv3 frags in AGPRs --------
  bf16x8 w1f[2][2];
  #pragma unroll
  for (int m = 0; m < 2; ++m)
    #pragma unroll
    for (int ks = 0; ks < 2; ++ks)
      w1f[m][ks] = *(const bf16x8*)(w1p + ((2*w + m) * 16 + lc) * 64 + ks * 32 + lk * 8);
  i32x4 ag2[16], ag3[8];
  #pragma unroll
  for (int ks = 0; ks < 16; ++ks) {
    bf16x8 t = *(const bf16x8*)(w2p + (w * 16 + lc) * 512 + ks * 32 + lk * 8);
    i32x4 u = __builtin_bit_cast(i32x4, t);
    asm("" : "=a"(ag2[ks]) : "0"(u));
  }
  #pragma unroll
  for (int ks = 0; ks < 8; ++ks) {
    bf16x8 t = *(const bf16x8*)(w3p + (w * 16 + lc) * 256 + ks * 32 + lk * 8);
    i32x4 u = __builtin_bit_cast(i32x4, t);
    asm("" : "=a"(ag3[ks]) : "0"(u));
  }

  for (int i = tid; i < 400; i += 256) xb[i] = f2bf(x[b * 400 + i]);
  __syncthreads();

  // ---- build im2col A1 [p][k]: thread owns k-pair (2k0,2k0+1), writes u32 ----
  {
    int k0 = (tid & 31) * 2;
    int p0 = tid >> 5;
    int c0 = k0 / 9, r90 = k0 % 9;
    int c1 = (k0 + 1) / 9, r91 = (k0 + 1) % 9;
    int i0 = c0 * 100 + (r90 / 3) * 10 + (r90 % 3);
    int i1 = c1 * 100 + (r91 / 3) * 10 + (r91 % 3);
    bool act = k0 < 36;
    #pragma unroll
    for (int j = 0; j < 8; ++j) {
      int p = p0 + j * 8;
      int px = (p >> 3) * 10 + (p & 7);
      unsigned v = 0;
      if (act) {
        unsigned short va = (unsigned short)xb[i0 + px];
        unsigned short vb = (unsigned short)xb[i1 + px];
        v = (unsigned)va | ((unsigned)vb << 16);
      }
      *(unsigned*)((char*)A1 + p * 144 + k0 * 2) = v;
    }
  }
  __syncthreads();

  // ---- conv1: wave w -> oc-tiles {2w,2w+1}; A=w1f (VGPR), B=A1[p][k]; K=64 ----
  f32x4 acc1[2][4];
  #pragma unroll
  for (int m = 0; m < 2; ++m)
    #pragma unroll
    for (int n = 0; n < 4; ++n) acc1[m][n] = z4;
  #pragma unroll
  for (int ks = 0; ks < 2; ++ks)
    #pragma unroll
    for (int n = 0; n < 4; ++n) {
      bf16x8 bf = *(const bf16x8*)(A1 + (n * 16 + lc) * 72 + ks * 32 + lk * 8);
      acc1[0][n] = MFMA(w1f[0][ks], bf, acc1[0][n]);
      acc1[1][n] = MFMA(w1f[1][ks], bf, acc1[1][n]);
    }
  #pragma unroll
  for (int m = 0; m < 2; ++m) {
    int oc0 = (2*w + m) * 16 + lk * 4;
    float4 bb = *(const float4*)(b1 + oc0);
    #pragma unroll
    for (int n = 0; n < 4; ++n) {
      int p = n * 16 + lc;
      union { short s[4]; unsigned long long u; } pk;
      pk.s[0] = f2bf(fmaxf(acc1[m][n][0] + bb.x, 0.f));
      pk.s[1] = f2bf(fmaxf(acc1[m][n][1] + bb.y, 0.f));
      pk.s[2] = f2bf(fmaxf(acc1[m][n][2] + bb.z, 0.f));
      pk.s[3] = f2bf(fmaxf(acc1[m][n][3] + bb.w, 0.f));
      *(unsigned long long*)(a1 + p * 136 + oc0) = pk.u;
    }
  }
  __syncthreads();

  // ---- conv2: wave w -> oc-tile w; A=AGPR w2 frags, B=a1[p][k]; M=16,N=64,K=512 ----
  f32x4 acc2[4];
  #pragma unroll
  for (int n = 0; n < 4; ++n) acc2[n] = z4;
  {
    int basep[4];
    #pragma unroll
    for (int n = 0; n < 4; ++n) {
      int p = n * 16 + lc; if (p > 48) p = 48;
      basep[n] = (p / 7) * 8 + p % 7;
    }
    const int off2v[4] = {0, 1, 8, 9};
    #pragma unroll
    for (int d = 0; d < 4; ++d) {
      #pragma unroll
      for (int k2 = 0; k2 < 4; ++k2) {
        int co = k2 * 32 + lk * 8;
        #pragma unroll
        for (int n = 0; n < 4; ++n) {
          bf16x8 bf = *(const bf16x8*)(a1 + (basep[n] + off2v[d]) * 136 + co);
          asm volatile("v_mfma_f32_16x16x32_bf16 %0, %1, %2, %0"
                       : "+v"(acc2[n]) : "a"(ag2[d * 4 + k2]), "v"(bf));
        }
      }
    }
  }
  {
    int oc0 = w * 16 + lk * 4;
    float4 bb = *(const float4*)(b2 + oc0);
    #pragma unroll
    for (int n = 0; n < 4; ++n) {
      int p = n * 16 + lc;
      if (p < 49) {
        union { short s[4]; unsigned long long u; } pk;
        pk.s[0] = f2bf(fmaxf(acc2[n][0] + bb.x, 0.f));
        pk.s[1] = f2bf(fmaxf(acc2[n][1] + bb.y, 0.f));
        pk.s[2] = f2bf(fmaxf(acc2[n][2] + bb.z, 0.f));
        pk.s[3] = f2bf(fmaxf(acc2[n][3] + bb.w, 0.f));
        *(unsigned long long*)(a2 + p * 72 + oc0) = pk.u;
      }
    }
  }
  __syncthreads();

  // ---- conv3: wave w -> oc-tile w; A=AGPR w3 frags, B=a2[p][k]; M=16,N=48,K=256 ----
  f32x4 acc3[3];
  #pragma unroll
  for (int n = 0; n < 3; ++n) acc3[n] = z4;
  {
    int basep[3];
    #pragma unroll
    for (int n = 0; n < 3; ++n) {
      int p = n * 16 + lc; if (p > 35) p = 35;
      basep[n] = (p / 6) * 7 + p % 6;
    }
    const int off3v[4] = {0, 1, 7, 8};
    #pragma unroll
    for (int d = 0; d < 4; ++d) {
      #pragma unroll
      for (int k2 = 0; k2 < 2; ++k2) {
        int co = k2 * 32 + lk * 8;
        #pragma unroll
        for (int n = 0; n < 3; ++n) {
          bf16x8 bf = *(const bf16x8*)(a2 + (basep[n] + off3v[d]) * 72 + co);
          asm volatile("v_mfma_f32_16x16x32_bf16 %0, %1, %2, %0"
                       : "+v"(acc3[n]) : "a"(ag3[d * 2 + k2]), "v"(bf));
        }
      }
    }
  }
  // ---- epilogue: bias+relu, * attn, + PE. Factored exp: freq = K0 * r18^e * r8^n;
  //      parity of k = (oc*36+p)&1 = lc&1 (wave-lane fixed). ----
  {
    int oc0 = w * 16 + lk * 4;
    float4 bb = *(const float4*)(b3 + oc0);
    float4 av = *(const float4*)(attn + b * 64 + oc0);
    float sf = (float)steps[b];
    const float C = (float)(-2.0 * (9.210340371976184 / 2304.0));  // -2*ln(1e4)/2304
    float rE = __expf(18.f * C);          // ratio per +1 oc
    float rN = __expf(8.f * C);           // ratio per +16 p
    float fe = sf * __expf(C * (float)(18 * oc0 + (lc >> 1)));
    #pragma unroll
    for (int e = 0; e < 4; ++e) {
      float bbe = (e == 0) ? bb.x : (e == 1) ? bb.y : (e == 2) ? bb.z : bb.w;
      float ave = (e == 0) ? av.x : (e == 1) ? av.y : (e == 2) ? av.z : av.w;
      float fn = fe;
      #pragma unroll
      for (int n = 0; n < 3; ++n) {
        int p = n * 16 + lc;
        if (p < 36) {
          float v = fmaxf(acc3[n][e] + bbe, 0.f) * ave;
          float pe = (lc & 1) ? __cosf(fn) : __sinf(fn);
          fst[(oc0 + e) * 36 + p] = f2bf(v + pe);
        }
        fn *= rN;
      }
      fe *= rE;
    }
  }
  __syncthreads();
  // ---- write flatT in k_lin A-fragment tiling: [mt][kc][lane][8] ----
  for (int i = tid; i < 288; i += 256) {
    int addr = (((b >> 4) * 72 + (i >> 2)) << 9) + ((((i & 3) << 4) + (b & 15)) << 3);
    *(bf16x8*)(flatT + addr) = *(const bf16x8*)(fst + i * 8);
  }
}

// ---------------- lin (M=4096,N=256,K=2304) + relu + partial critic ----------------
__global__ __launch_bounds__(256, 4) void k_lin(
    const short* __restrict__ flatT, const short* __restrict__ linp2,
    const float* __restrict__ lin_b, const float* __restrict__ crit_w,
    float* __restrict__ part)
{
  __shared__ float hidT[16][68];
  __shared__ float cwL[4][65];
  const int tid = threadIdx.x;
  const int w = tid >> 6, l = tid & 63, lr = l & 15, lk = l >> 4;
  const int mt = blockIdx.x >> 2;
  const int cg = blockIdx.x & 3;
  const int rt = cg * 4 + w;
  const f32x4 z4 = {0.f, 0.f, 0.f, 0.f};

  {
    int oc = tid >> 6, c = tid & 63;
    cwL[oc][c] = crit_w[oc * 256 + cg * 64 + c];
  }

  const short* Ab = flatT + mt * 72 * 512 + l * 8;
  const short* Bb = linp2 + rt * 72 * 512 + l * 8;

  bf16x8 aP[4], bP[4], aN[4], bN[4];
  f32x4 acc = z4;
  #pragma unroll
  for (int j = 0; j < 4; ++j) {
    aP[j] = *(const bf16x8*)(Ab + j * 512);
    bP[j] = *(const bf16x8*)(Bb + j * 512);
  }
  #pragma unroll
  for (int kb = 0; kb < 72; kb += 8) {
    #pragma unroll
    for (int j = 0; j < 4; ++j) {
      aN[j] = *(const bf16x8*)(Ab + (kb + 4 + j) * 512);
      bN[j] = *(const bf16x8*)(Bb + (kb + 4 + j) * 512);
    }
    #pragma unroll
    for (int j = 0; j < 4; ++j) acc = MFMA(aP[j], bP[j], acc);
    if (kb + 8 < 72) {
      #pragma unroll
      for (int j = 0; j < 4; ++j) {
        aP[j] = *(const bf16x8*)(Ab + (kb + 8 + j) * 512);
        bP[j] = *(const bf16x8*)(Bb + (kb + 8 + j) * 512);
      }
    }
    #pragma unroll
    for (int j = 0; j < 4; ++j) acc = MFMA(aN[j], bN[j], acc);
  }

  {
    float bb = lin_b[cg * 64 + w * 16 + lr];
    #pragma unroll
    for (int e = 0; e < 4; ++e)
      hidT[lk * 4 + e][w * 16 + lr] = fmaxf(acc[e] + bb, 0.f);
  }
  __syncthreads();
  if (tid < 64) {
    int r = tid >> 2, oc = tid & 3;
    float s = 0.f;
    #pragma unroll 8
    for (int c = 0; c < 64; ++c) s += hidT[r][c] * cwL[oc][c];
    part[(cg * 4096 + mt * 16 + r) * 4 + oc] = s;
  }
}

// ---------------- critic finish ----------------
__global__ void k_crit(const float* __restrict__ part, const float* __restrict__ crit_b,
                       float* __restrict__ out)
{
  int i = blockIdx.x * 256 + threadIdx.x;
  if (i < 16384) {
    out[i] = crit_b[i & 3] + ((part[i] + part[16384 + i]) + (part[32768 + i] + part[49152 + i]));
  }
}

extern "C" void kernel_launch(void* const* d_in, const int* in_sizes, int n_in,
                              void* d_out, int out_size, void* d_ws, size_t ws_size,
                              hipStream_t stream) {
  const float* x    = (const float*)d_in[0];
  const int*   inst = (const int*)  d_in[1];
  const int*   stp  = (const int*)  d_in[2];
  const float* w1   = (const float*)d_in[3];
  const float* b1   = (const float*)d_in[4];
  const float* w2   = (const float*)d_in[5];
  const float* b2   = (const float*)d_in[6];
  const float* w3   = (const float*)d_in[7];
  const float* b3   = (const float*)d_in[8];
  const float* emb  = (const float*)d_in[9];
  const float* wih  = (const float*)d_in[10];
  const float* whh  = (const float*)d_in[11];
  const float* bih  = (const float*)d_in[12];
  const float* bhh  = (const float*)d_in[13];
  const float* aw   = (const float*)d_in[14];
  const float* ab   = (const float*)d_in[15];
  const float* lw   = (const float*)d_in[16];
  const float* lb   = (const float*)d_in[17];
  const float* cwp  = (const float*)d_in[18];
  const float* cb   = (const float*)d_in[19];
  float* out = (float*)d_out;

  char* ws = (char*)d_ws;
  short* flat  = (short*)(ws + 0);          // 18874368 (fragment-tiled)
  float* attnv = (float*)(ws + 18874368);   // 1048576
  short* w1p   = (short*)(ws + 19922944);   // 16384
  short* w2p   = (short*)(ws + 19939328);   // 65536
  short* w3p   = (short*)(ws + 20004864);   // 32768
  short* wihp  = (short*)(ws + 20037632);   // 49152
  short* whhp  = (short*)(ws + 20086784);   // 393216
  short* attnp = (short*)(ws + 20480000);   // 32768
  short* linp  = (short*)(ws + 20512768);   // 1179648
  float* part  = (float*)(ws + 21692416);   // 262144 -> total 21954560

  k_prep<<<dim3(3456), dim3(256), 0, stream>>>(w1, w2, w3, wih, whh, aw, lw,
                                               w1p, w2p, w3p, wihp, whhp, attnp, linp);
  k_gru<<<dim3(256), dim3(512), 0, stream>>>(inst, emb, wihp, whhp, bih, bhh,
                                             attnp, ab, attnv);
  k_conv<<<dim3(4096), dim3(256), 0, stream>>>(x, w1p, b1, w2p, b2, w3p, b3,
                                               attnv, stp, flat);
  k_lin<<<dim3(1024), dim3(256), 0, stream>>>(flat, linp, lb, cwp, part);
  k_crit<<<dim3(64), dim3(256), 0, stream>>>(part, cb, out);
}

// Round 11
// 136.407 us; speedup vs baseline: 1.2956x; 1.2956x over previous
//
#include <hip/hip_runtime.h>

using bf16x8 = __attribute__((ext_vector_type(8))) short;
using f32x4  = __attribute__((ext_vector_type(4))) float;
using i32x4  = __attribute__((ext_vector_type(4))) int;

#define MFMA(a,b,c) __builtin_amdgcn_mfma_f32_16x16x32_bf16((a),(b),(c),0,0,0)

__device__ __forceinline__ short f2bf(float f) {
  unsigned u = __builtin_bit_cast(unsigned, f);
  u += 0x7FFFu + ((u >> 16) & 1u);   // RNE
  return (short)(u >> 16);
}
__device__ __forceinline__ float sigm(float x) { return 1.0f / (1.0f + __expf(-x)); }
__device__ __forceinline__ float tanh_(float x) { return 2.0f * sigm(2.0f * x) - 1.0f; }

__device__ __forceinline__ bf16x8 pack8(float4 a, float4 b) {
  bf16x8 r;
  r[0]=f2bf(a.x); r[1]=f2bf(a.y); r[2]=f2bf(a.z); r[3]=f2bf(a.w);
  r[4]=f2bf(b.x); r[5]=f2bf(b.y); r[6]=f2bf(b.z); r[7]=f2bf(b.w);
  return r;
}

// ---------------- prep: weights -> bf16, MFMA-fragment-tiled layouts ----------------
__global__ void k_prep(const float* __restrict__ w1, const float* __restrict__ w2,
                       const float* __restrict__ w3, const float* __restrict__ wih,
                       const float* __restrict__ whh, const float* __restrict__ aw,
                       const float* __restrict__ lw,
                       short* __restrict__ w1p, short* __restrict__ w2p, short* __restrict__ w3p,
                       short* __restrict__ wihp, short* __restrict__ whhp,
                       short* __restrict__ attnp, short* __restrict__ linp)
{
  int i = blockIdx.x * 256 + threadIdx.x;
  if (i < 8192) {                       // w1p [128][64], k=c*9+dy*3+dx, pad 36..63 = 0
    int o = i >> 6, k = i & 63;
    float v = 0.f;
    if (k < 36) { int c = k / 9, r9 = k % 9; v = w1[((o*4 + c)*3 + r9/3)*3 + (r9%3)]; }
    w1p[i] = f2bf(v); return;
  }
  i -= 8192;
  if (i < 32768) {                      // w2p [64][512], k=(dy*2+dx)*128+c
    int o = i >> 9, k = i & 511;
    int dydx = k >> 7, c = k & 127;
    w2p[i] = f2bf(w2[((o*128 + c)*2 + (dydx>>1))*2 + (dydx&1)]); return;
  }
  i -= 32768;
  if (i < 16384) {                      // w3p [64][256], k=(dy*2+dx)*64+c
    int o = i >> 8, k = i & 255;
    int dydx = k >> 6, c = k & 63;
    w3p[i] = f2bf(w3[((o*64 + c)*2 + (dydx>>1))*2 + (dydx&1)]); return;
  }
  i -= 16384;
  if (i < 24576) {                      // wih2: [rt][kc(0..3)][r16][k8]
    int k8 = i & 7, r16 = (i >> 3) & 15, kc = (i >> 7) & 3, rt = i >> 9;
    wihp[i] = f2bf(wih[(rt*16 + r16) * 32 + kc*8 + k8]); return;
  }
  i -= 24576;
  if (i < 196608) {                     // whh2: [rt(0..47)][kc(0..31)][r16][k8]
    int k8 = i & 7, r16 = (i >> 3) & 15, kc = (i >> 7) & 31, rt = i >> 12;
    whhp[i] = f2bf(whh[(rt*16 + r16) * 256 + kc*8 + k8]); return;
  }
  i -= 196608;
  if (i < 16384) {                      // attn2: [rt(0..3)][kc(0..31)][r16][k8]
    int k8 = i & 7, r16 = (i >> 3) & 15, kc = (i >> 7) & 31, rt = i >> 12;
    attnp[i] = f2bf(aw[(rt*16 + r16) * 256 + kc*8 + k8]); return;
  }
  i -= 16384;
  if (i < 589824) {                     // linp2: [rt(0..15)][kc(0..71)][lane(0..63)][e(0..7)]
    int j = i >> 9;
    int rt = j / 72, kc = j - rt * 72;
    int q = i & 511, lane = q >> 3, e = q & 7;
    int row = rt * 16 + (lane & 15);
    int k = kc * 32 + (lane >> 4) * 8 + e;
    linp[i] = f2bf(lw[row * 2304 + k]); return;
  }
}

// ---------------- GRU: whh pinned (ks0 VGPR, ks1-6 AGPR fed to MFMA directly, ks7 LDS) ----------------
__global__ __launch_bounds__(512, 2) void k_gru(
    const int* __restrict__ inst, const float* __restrict__ emb_w,
    const short* __restrict__ wih2, const short* __restrict__ whh2,
    const float* __restrict__ b_ih, const float* __restrict__ b_hh,
    const short* __restrict__ attn2, const float* __restrict__ attn_b,
    float* __restrict__ attn_out)
{
  __shared__ short hA[16 * 256];       // bf16 h double-buffer, XOR-swizzled (row 512B)
  __shared__ short hB[16 * 256];
  __shared__ short xfL[16 * 64 * 8];   // [t][lane][8]  (16KB)
  __shared__ short wihL[6 * 512 * 8];  // [nt][tid][8]  (48KB)
  __shared__ short wf7L[6 * 512 * 8];  // whh ks=7 fragments (48KB)

  const int tid = threadIdx.x;
  const int w = tid >> 6, l = tid & 63, lr = l & 15, lk = l >> 4;
  const int b0 = blockIdx.x * 16;
  const f32x4 z4 = {0.f, 0.f, 0.f, 0.f};

  int rtile[6], rowW[6];
  #pragma unroll
  for (int nt = 0; nt < 6; ++nt) {
    rtile[nt] = (nt >> 1) * 16 + w * 2 + (nt & 1);
    rowW[nt]  = rtile[nt] * 16 + lr;
  }

  // -------- preload whh: ks0 -> VGPR, ks1..6 -> AGPR (pinned), ks7 -> LDS --------
  bf16x8 wf0[6];
  i32x4 ag[6][6];
  #pragma unroll
  for (int nt = 0; nt < 6; ++nt) {
    wf0[nt] = *(const bf16x8*)(whh2 + ((rtile[nt]*32 + lk)*16 + lr)*8);
    #pragma unroll
    for (int ks = 1; ks < 7; ++ks) {
      bf16x8 t = *(const bf16x8*)(whh2 + ((rtile[nt]*32 + ks*4 + lk)*16 + lr)*8);
      i32x4 u = __builtin_bit_cast(i32x4, t);
      asm("" : "=a"(ag[nt][ks-1]) : "0"(u));   // pin into AGPR tuple
    }
    *(bf16x8*)(wf7L + (nt*512 + tid)*8) =
        *(const bf16x8*)(whh2 + ((rtile[nt]*32 + 28 + lk)*16 + lr)*8);
    *(bf16x8*)(wihL + (nt*512 + tid)*8) =
        *(const bf16x8*)(wih2 + ((rtile[nt]*4 + lk)*16 + lr)*8);
  }

  float biasRZ[4], bihN[2], bhhN[2];
  #pragma unroll
  for (int nt = 0; nt < 4; ++nt) biasRZ[nt] = b_ih[rowW[nt]] + b_hh[rowW[nt]];
  #pragma unroll
  for (int s = 0; s < 2; ++s) { bihN[s] = b_ih[rowW[4+s]]; bhhN[s] = b_hh[rowW[4+s]]; }

  #pragma unroll
  for (int f = tid; f < 1024; f += 512) {
    int t = f >> 6, ll = f & 63, llr = ll & 15, llk = ll >> 4;
    int id = inst[(b0 + llr) * 16 + t];
    const float* ep = emb_w + id * 32 + llk * 8;
    *(bf16x8*)(xfL + f * 8) = pack8(*(const float4*)(ep), *(const float4*)(ep + 4));
  }

  for (int i = tid; i < 4096; i += 512) hA[i] = 0;

  float hOld[2][4];
  #pragma unroll
  for (int s = 0; s < 2; ++s)
    #pragma unroll
    for (int e = 0; e < 4; ++e) hOld[s][e] = 0.f;

  __syncthreads();

  for (int t = 0; t < 16; ++t) {
    const short* hr = (t & 1) ? hB : hA;
    short*       hw = (t & 1) ? hA : hB;

    bf16x8 xf = *(const bf16x8*)(xfL + (t * 64 + l) * 8);
    f32x4 acc[6], gin[2];
    #pragma unroll
    for (int nt = 0; nt < 4; ++nt)
      acc[nt] = MFMA(xf, *(const bf16x8*)(wihL + (nt*512 + tid)*8), z4);
    #pragma unroll
    for (int s = 0; s < 2; ++s)
      gin[s] = MFMA(xf, *(const bf16x8*)(wihL + ((4+s)*512 + tid)*8), z4);
    acc[4] = z4; acc[5] = z4;

    {   // ks = 0 from VGPR
      int byte = (lr * 512 + lk * 16) ^ ((lr & 7) << 4);
      bf16x8 hf = *(const bf16x8*)((const char*)hr + byte);
      #pragma unroll
      for (int nt = 0; nt < 6; ++nt) acc[nt] = MFMA(hf, wf0[nt], acc[nt]);
    }
    #pragma unroll
    for (int ks = 1; ks < 7; ++ks) {    // ks = 1..6: MFMA reads B straight from AGPR
      int byte = (lr * 512 + ks * 64 + lk * 16) ^ ((lr & 7) << 4);
      bf16x8 hf = *(const bf16x8*)((const char*)hr + byte);
      #pragma unroll
      for (int nt = 0; nt < 6; ++nt)
        asm volatile("v_mfma_f32_16x16x32_bf16 %0, %1, %2, %0"
                     : "+v"(acc[nt]) : "v"(hf), "a"(ag[nt][ks-1]));
    }
    {   // ks = 7 from LDS stash
      int byte = (lr * 512 + 7 * 64 + lk * 16) ^ ((lr & 7) << 4);
      bf16x8 hf = *(const bf16x8*)((const char*)hr + byte);
      #pragma unroll
      for (int nt = 0; nt < 6; ++nt) {
        bf16x8 bw = *(const bf16x8*)(wf7L + (nt*512 + tid)*8);
        acc[nt] = MFMA(hf, bw, acc[nt]);
      }
    }

    #pragma unroll
    for (int s = 0; s < 2; ++s)
      #pragma unroll
      for (int e = 0; e < 4; ++e) {
        float r  = sigm(acc[s][e]     + biasRZ[s]);
        float zz = sigm(acc[2 + s][e] + biasRZ[2 + s]);
        float nn = tanh_(gin[s][e] + bihN[s] + r * (acc[4 + s][e] + bhhN[s]));
        float hn = (1.0f - zz) * nn + zz * hOld[s][e];
        hOld[s][e] = hn;
        int row = lk * 4 + e;
        int col = w * 32 + s * 16 + lr;
        int byte = (row * 512 + col * 2) ^ ((row & 7) << 4);
        *(short*)((char*)hw + byte) = f2bf(hn);
      }
    __syncthreads();
  }

  if (w < 4) {
    f32x4 acc = z4;
    #pragma unroll
    for (int ks = 0; ks < 8; ++ks) {
      int byte = (lr * 512 + ks * 64 + lk * 16) ^ ((lr & 7) << 4);
      bf16x8 hf = *(const bf16x8*)((const char*)hA + byte);
      bf16x8 bw = *(const bf16x8*)(attn2 + ((w*32 + ks*4 + lk)*16 + lr)*8);
      acc = MFMA(hf, bw, acc);
    }
    float bb = attn_b[w * 16 + lr];
    #pragma unroll
    for (int e = 0; e < 4; ++e) {
      int row = lk * 4 + e;
      attn_out[(b0 + row) * 64 + w * 16 + lr] = sigm(acc[e] + bb);
    }
  }
}

// ---------------- fused conv1+conv2+conv3 + gating + PE -> flatT ----------------
// TWO samples per block, 256 thr (4 waves). Round-8 structure, doubled per-wave ILP:
// each phase runs two independent samples' dependency chains interleaved, and
// barriers/weight-loads amortize over 2 samples. LDS 53.2KB -> 3 blocks/CU.
__global__ __launch_bounds__(256, 3) void k_conv(
    const float* __restrict__ x,
    const short* __restrict__ w1p, const float* __restrict__ b1,
    const short* __restrict__ w2p, const float* __restrict__ b2,
    const short* __restrict__ w3p, const float* __restrict__ b3,
    const float* __restrict__ attn, const int* __restrict__ steps,
    short* __restrict__ flatT)
{
  __shared__ short smem[26624];
  // region X_s (4608 sh each): A1 (im2col [p][k], stride 144B) then a2 ([p][oc], 144B)
  // region Y_s (8704 sh each): xb[400], then a1 ([p][oc], stride 272B), then fst[2304]
  short* const A1s[2]  = { smem,        smem + 4608 };
  short* const a2s[2]  = { smem,        smem + 4608 };
  short* const xbs[2]  = { smem + 9216, smem + 9216 + 8704 };
  short* const a1s[2]  = { smem + 9216, smem + 9216 + 8704 };
  short* const fsts[2] = { smem + 9216, smem + 9216 + 8704 };

  const int tid = threadIdx.x;
  const int w = tid >> 6, l = tid & 63, lc = l & 15, lk = l >> 4;
  const int b0 = blockIdx.x * 2;
  const f32x4 z4 = {0.f, 0.f, 0.f, 0.f};

  for (int i = tid; i < 400; i += 256) {
    xbs[0][i] = f2bf(x[b0 * 400 + i]);
    xbs[1][i] = f2bf(x[(b0 + 1) * 400 + i]);
  }
  __syncthreads();

  // ---- im2col into A1s[s] [p][k]: thread owns k-pair (2k0,2k0+1), writes u32 ----
  {
    int k0 = (tid & 31) * 2;
    int p0 = tid >> 5;
    int c0 = k0 / 9, r90 = k0 % 9;
    int c1 = (k0 + 1) / 9, r91 = (k0 + 1) % 9;
    int i0 = c0 * 100 + (r90 / 3) * 10 + (r90 % 3);
    int i1 = c1 * 100 + (r91 / 3) * 10 + (r91 % 3);
    bool act = k0 < 36;
    #pragma unroll
    for (int s = 0; s < 2; ++s)
      #pragma unroll
      for (int j = 0; j < 8; ++j) {
        int p = p0 + j * 8;
        int px = (p >> 3) * 10 + (p & 7);
        unsigned v = 0;
        if (act) {
          unsigned short va = (unsigned short)xbs[s][i0 + px];
          unsigned short vb = (unsigned short)xbs[s][i1 + px];
          v = (unsigned)va | ((unsigned)vb << 16);
        }
        *(unsigned*)((char*)A1s[s] + p * 144 + k0 * 2) = v;
      }
  }
  __syncthreads();

  // ---- conv1: wave w -> oc-tiles {2w,2w+1}; A=w1p[oc][k], B=A1[p][k]; K=64 ----
  f32x4 acc1[2][2][4];
  #pragma unroll
  for (int s = 0; s < 2; ++s)
    #pragma unroll
    for (int m = 0; m < 2; ++m)
      #pragma unroll
      for (int n = 0; n < 4; ++n) acc1[s][m][n] = z4;
  #pragma unroll
  for (int ks = 0; ks < 2; ++ks) {
    bf16x8 af0 = *(const bf16x8*)(w1p + ((2*w)     * 16 + lc) * 64 + ks * 32 + lk * 8);
    bf16x8 af1 = *(const bf16x8*)(w1p + ((2*w + 1) * 16 + lc) * 64 + ks * 32 + lk * 8);
    #pragma unroll
    for (int n = 0; n < 4; ++n)
      #pragma unroll
      for (int s = 0; s < 2; ++s) {
        bf16x8 bf = *(const bf16x8*)(A1s[s] + (n * 16 + lc) * 72 + ks * 32 + lk * 8);
        acc1[s][0][n] = MFMA(af0, bf, acc1[s][0][n]);
        acc1[s][1][n] = MFMA(af1, bf, acc1[s][1][n]);
      }
  }
  #pragma unroll
  for (int m = 0; m < 2; ++m) {
    int oc0 = (2*w + m) * 16 + lk * 4;
    float4 bb = *(const float4*)(b1 + oc0);
    #pragma unroll
    for (int s = 0; s < 2; ++s)
      #pragma unroll
      for (int n = 0; n < 4; ++n) {
        int p = n * 16 + lc;
        union { short sh[4]; unsigned long long u; } pk;
        pk.sh[0] = f2bf(fmaxf(acc1[s][m][n][0] + bb.x, 0.f));
        pk.sh[1] = f2bf(fmaxf(acc1[s][m][n][1] + bb.y, 0.f));
        pk.sh[2] = f2bf(fmaxf(acc1[s][m][n][2] + bb.z, 0.f));
        pk.sh[3] = f2bf(fmaxf(acc1[s][m][n][3] + bb.w, 0.f));
        *(unsigned long long*)(a1s[s] + p * 136 + oc0) = pk.u;
      }
  }
  __syncthreads();

  // ---- conv2: wave w -> oc-tile w; A=w2p[oc][k], B=a1[p][k]; M=16,N=64,K=512 ----
  f32x4 acc2[2][4];
  #pragma unroll
  for (int s = 0; s < 2; ++s)
    #pragma unroll
    for (int n = 0; n < 4; ++n) acc2[s][n] = z4;
  {
    int basep[4];
    #pragma unroll
    for (int n = 0; n < 4; ++n) {
      int p = n * 16 + lc; if (p > 48) p = 48;
      basep[n] = (p / 7) * 8 + p % 7;
    }
    const int off2v[4] = {0, 1, 8, 9};
    #pragma unroll
    for (int d = 0; d < 4; ++d) {
      #pragma unroll
      for (int k2 = 0; k2 < 4; ++k2) {
        bf16x8 af = *(const bf16x8*)(w2p + (w * 16 + lc) * 512 + d * 128 + k2 * 32 + lk * 8);
        int co = k2 * 32 + lk * 8;
        #pragma unroll
        for (int n = 0; n < 4; ++n)
          #pragma unroll
          for (int s = 0; s < 2; ++s) {
            bf16x8 bf = *(const bf16x8*)(a1s[s] + (basep[n] + off2v[d]) * 136 + co);
            acc2[s][n] = MFMA(af, bf, acc2[s][n]);
          }
      }
    }
  }
  {
    int oc0 = w * 16 + lk * 4;
    float4 bb = *(const float4*)(b2 + oc0);
    #pragma unroll
    for (int s = 0; s < 2; ++s)
      #pragma unroll
      for (int n = 0; n < 4; ++n) {
        int p = n * 16 + lc;
        if (p < 49) {
          union { short sh[4]; unsigned long long u; } pk;
          pk.sh[0] = f2bf(fmaxf(acc2[s][n][0] + bb.x, 0.f));
          pk.sh[1] = f2bf(fmaxf(acc2[s][n][1] + bb.y, 0.f));
          pk.sh[2] = f2bf(fmaxf(acc2[s][n][2] + bb.z, 0.f));
          pk.sh[3] = f2bf(fmaxf(acc2[s][n][3] + bb.w, 0.f));
          *(unsigned long long*)(a2s[s] + p * 72 + oc0) = pk.u;
        }
      }
  }
  __syncthreads();

  // ---- conv3: wave w -> oc-tile w; A=w3p[oc][k], B=a2[p][k]; M=16,N=48,K=256 ----
  f32x4 acc3[2][3];
  #pragma unroll
  for (int s = 0; s < 2; ++s)
    #pragma unroll
    for (int n = 0; n < 3; ++n) acc3[s][n] = z4;
  {
    int basep[3];
    #pragma unroll
    for (int n = 0; n < 3; ++n) {
      int p = n * 16 + lc; if (p > 35) p = 35;
      basep[n] = (p / 6) * 7 + p % 6;
    }
    const int off3v[4] = {0, 1, 7, 8};
    #pragma unroll
    for (int d = 0; d < 4; ++d) {
      #pragma unroll
      for (int k2 = 0; k2 < 2; ++k2) {
        bf16x8 af = *(const bf16x8*)(w3p + (w * 16 + lc) * 256 + d * 64 + k2 * 32 + lk * 8);
        int co = k2 * 32 + lk * 8;
        #pragma unroll
        for (int n = 0; n < 3; ++n)
          #pragma unroll
          for (int s = 0; s < 2; ++s) {
            bf16x8 bf = *(const bf16x8*)(a2s[s] + (basep[n] + off3v[d]) * 72 + co);
            acc3[s][n] = MFMA(af, bf, acc3[s][n]);
          }
      }
    }
  }
  // ---- epilogue: bias+relu, * attn, + PE (factored exp; parity of k = lc&1) ----
  {
    int oc0 = w * 16 + lk * 4;
    float4 bb = *(const float4*)(b3 + oc0);
    const float C = (float)(-2.0 * (9.210340371976184 / 2304.0));  // -2*ln(1e4)/2304
    float rE = __expf(18.f * C);
    float rN = __expf(8.f * C);
    float base = __expf(C * (float)(18 * oc0 + (lc >> 1)));
    #pragma unroll
    for (int s = 0; s < 2; ++s) {
      float4 av = *(const float4*)(attn + (b0 + s) * 64 + oc0);
      float fe = (float)steps[b0 + s] * base;
      #pragma unroll
      for (int e = 0; e < 4; ++e) {
        float bbe = (e == 0) ? bb.x : (e == 1) ? bb.y : (e == 2) ? bb.z : bb.w;
        float ave = (e == 0) ? av.x : (e == 1) ? av.y : (e == 2) ? av.z : av.w;
        float fn = fe;
        #pragma unroll
        for (int n = 0; n < 3; ++n) {
          int p = n * 16 + lc;
          if (p < 36) {
            float v = fmaxf(acc3[s][n][e] + bbe, 0.f) * ave;
            float pe = (lc & 1) ? __cosf(fn) : __sinf(fn);
            fsts[s][(oc0 + e) * 36 + p] = f2bf(v + pe);
          }
          fn *= rN;
        }
        fe *= rE;
      }
    }
  }
  __syncthreads();
  // ---- write flatT in k_lin A-fragment tiling: [mt][kc][lane][8] ----
  #pragma unroll
  for (int s = 0; s < 2; ++s) {
    int b = b0 + s;
    for (int i = tid; i < 288; i += 256) {
      int addr = (((b >> 4) * 72 + (i >> 2)) << 9) + ((((i & 3) << 4) + (b & 15)) << 3);
      *(bf16x8*)(flatT + addr) = *(const bf16x8*)(fsts[s] + i * 8);
    }
  }
}

// ---------------- lin (M=4096,N=256,K=2304) + relu + partial critic ----------------
__global__ __launch_bounds__(256, 4) void k_lin(
    const short* __restrict__ flatT, const short* __restrict__ linp2,
    const float* __restrict__ lin_b, const float* __restrict__ crit_w,
    float* __restrict__ part)
{
  __shared__ float hidT[16][68];
  __shared__ float cwL[4][65];
  const int tid = threadIdx.x;
  const int w = tid >> 6, l = tid & 63, lr = l & 15, lk = l >> 4;
  const int mt = blockIdx.x >> 2;
  const int cg = blockIdx.x & 3;
  const int rt = cg * 4 + w;
  const f32x4 z4 = {0.f, 0.f, 0.f, 0.f};

  {
    int oc = tid >> 6, c = tid & 63;
    cwL[oc][c] = crit_w[oc * 256 + cg * 64 + c];
  }

  const short* Ab = flatT + mt * 72 * 512 + l * 8;
  const short* Bb = linp2 + rt * 72 * 512 + l * 8;

  bf16x8 aP[4], bP[4], aN[4], bN[4];
  f32x4 acc = z4;
  #pragma unroll
  for (int j = 0; j < 4; ++j) {
    aP[j] = *(const bf16x8*)(Ab + j * 512);
    bP[j] = *(const bf16x8*)(Bb + j * 512);
  }
  #pragma unroll
  for (int kb = 0; kb < 72; kb += 8) {
    #pragma unroll
    for (int j = 0; j < 4; ++j) {
      aN[j] = *(const bf16x8*)(Ab + (kb + 4 + j) * 512);
      bN[j] = *(const bf16x8*)(Bb + (kb + 4 + j) * 512);
    }
    #pragma unroll
    for (int j = 0; j < 4; ++j) acc = MFMA(aP[j], bP[j], acc);
    if (kb + 8 < 72) {
      #pragma unroll
      for (int j = 0; j < 4; ++j) {
        aP[j] = *(const bf16x8*)(Ab + (kb + 8 + j) * 512);
        bP[j] = *(const bf16x8*)(Bb + (kb + 8 + j) * 512);
      }
    }
    #pragma unroll
    for (int j = 0; j < 4; ++j) acc = MFMA(aN[j], bN[j], acc);
  }

  {
    float bb = lin_b[cg * 64 + w * 16 + lr];
    #pragma unroll
    for (int e = 0; e < 4; ++e)
      hidT[lk * 4 + e][w * 16 + lr] = fmaxf(acc[e] + bb, 0.f);
  }
  __syncthreads();
  if (tid < 64) {
    int r = tid >> 2, oc = tid & 3;
    float s = 0.f;
    #pragma unroll 8
    for (int c = 0; c < 64; ++c) s += hidT[r][c] * cwL[oc][c];
    part[(cg * 4096 + mt * 16 + r) * 4 + oc] = s;
  }
}

// ---------------- critic finish ----------------
__global__ void k_crit(const float* __restrict__ part, const float* __restrict__ crit_b,
                       float* __restrict__ out)
{
  int i = blockIdx.x * 256 + threadIdx.x;
  if (i < 16384) {
    out[i] = crit_b[i & 3] + ((part[i] + part[16384 + i]) + (part[32768 + i] + part[49152 + i]));
  }
}

extern "C" void kernel_launch(void* const* d_in, const int* in_sizes, int n_in,
                              void* d_out, int out_size, void* d_ws, size_t ws_size,
                              hipStream_t stream) {
  const float* x    = (const float*)d_in[0];
  const int*   inst = (const int*)  d_in[1];
  const int*   stp  = (const int*)  d_in[2];
  const float* w1   = (const float*)d_in[3];
  const float* b1   = (const float*)d_in[4];
  const float* w2   = (const float*)d_in[5];
  const float* b2   = (const float*)d_in[6];
  const float* w3   = (const float*)d_in[7];
  const float* b3   = (const float*)d_in[8];
  const float* emb  = (const float*)d_in[9];
  const float* wih  = (const float*)d_in[10];
  const float* whh  = (const float*)d_in[11];
  const float* bih  = (const float*)d_in[12];
  const float* bhh  = (const float*)d_in[13];
  const float* aw   = (const float*)d_in[14];
  const float* ab   = (const float*)d_in[15];
  const float* lw   = (const float*)d_in[16];
  const float* lb   = (const float*)d_in[17];
  const float* cwp  = (const float*)d_in[18];
  const float* cb   = (const float*)d_in[19];
  float* out = (float*)d_out;

  char* ws = (char*)d_ws;
  short* flat  = (short*)(ws + 0);          // 18874368 (fragment-tiled)
  float* attnv = (float*)(ws + 18874368);   // 1048576
  short* w1p   = (short*)(ws + 19922944);   // 16384
  short* w2p   = (short*)(ws + 19939328);   // 65536
  short* w3p   = (short*)(ws + 20004864);   // 32768
  short* wihp  = (short*)(ws + 20037632);   // 49152
  short* whhp  = (short*)(ws + 20086784);   // 393216
  short* attnp = (short*)(ws + 20480000);   // 32768
  short* linp  = (short*)(ws + 20512768);   // 1179648
  float* part  = (float*)(ws + 21692416);   // 262144 -> total 21954560

  k_prep<<<dim3(3456), dim3(256), 0, stream>>>(w1, w2, w3, wih, whh, aw, lw,
                                               w1p, w2p, w3p, wihp, whhp, attnp, linp);
  k_gru<<<dim3(256), dim3(512), 0, stream>>>(inst, emb, wihp, whhp, bih, bhh,
                                             attnp, ab, attnv);
  k_conv<<<dim3(2048), dim3(256), 0, stream>>>(x, w1p, b1, w2p, b2, w3p, b3,
                                               attnv, stp, flat);
  k_lin<<<dim3(1024), dim3(256), 0, stream>>>(flat, linp, lb, cwp, part);
  k_crit<<<dim3(64), dim3(256), 0, stream>>>(part, cb, out);
}